// Round 8
// baseline (167.745 us; speedup 1.0000x reference)
//
#include <hip/hip_runtime.h>
#include <math.h>

#define B_  4
#define C1_ 256
#define C2_ 256
#define H_  64
#define W_  64
#define HW_ 4096
#define KK_ 9

// ws byte offsets
#define WA_OFF    0u            // bf16 Wa[72][4][256][8]           (1,179,648 B)
#define XBF_OFF   1179648u      // bf16 xbf[B][C1][HW]              (8,388,608 B)
#define MIDX_OFF  9568256u      // int2  midx[B][9][4096]           (1,179,648 B)
#define MWGT_OFF  10747904u     // float4 mwgt[B][9][4096]          (2,359,296 B)
#define WOM_OFF   13107200u     // bf16 Wom[72][4][32][8]           (147,456 B)
#define BN_OFF    13254656u     // float inv[256]; bb[256]          (2,048 B)

typedef short bf16x8 __attribute__((ext_vector_type(8)));
typedef float f32x4 __attribute__((ext_vector_type(4)));

__device__ __forceinline__ unsigned f2bfu(float f) {
  unsigned u = __builtin_bit_cast(unsigned, f);
  return (u + 0x7FFFu + ((u >> 16) & 1u)) >> 16;
}

__device__ __forceinline__ float bfl(unsigned short u) {
  return __builtin_bit_cast(float, (unsigned)u << 16);
}

__device__ __forceinline__ void gload_lds16(const void* g, void* l) {
  __builtin_amdgcn_global_load_lds(
      (const __attribute__((address_space(1))) unsigned*)g,
      (__attribute__((address_space(3))) unsigned*)l, 16, 0, 0);
}

// grid 512: 8 XCDs; each XCD owns 32 consecutive rows of ONE batch.
__device__ __forceinline__ void decode_bid512(int bid, int& b, int& h, int& ph) {
  const int xcd = bid & 7, slot = bid >> 3;  // slot < 64
  b = xcd >> 1;
  h = (xcd & 1) * 32 + (slot >> 1);
  ph = slot & 1;
}

// ---------------------------------------------------------------------------
// prep: fused xcast + wt_perm + wom_perm/BN (unchanged from R7)
// ---------------------------------------------------------------------------
__global__ __launch_bounds__(256) void prep(
    const float* __restrict__ x, const float* __restrict__ w_om,
    const float* __restrict__ w_dcn, const float* __restrict__ bn_gamma,
    const float* __restrict__ bn_beta, const float* __restrict__ bn_mean,
    const float* __restrict__ bn_var, char* __restrict__ wsb) {
  const int bid = blockIdx.x;
  if (bid < 2048) {
    const int gid = (bid * 256 + threadIdx.x) * 8;
    const float4 v0 = *(const float4*)(x + gid);
    const float4 v1 = *(const float4*)(x + gid + 4);
    int4 o;
    o.x = f2bfu(v0.x) | (f2bfu(v0.y) << 16);
    o.y = f2bfu(v0.z) | (f2bfu(v0.w) << 16);
    o.z = f2bfu(v1.x) | (f2bfu(v1.y) << 16);
    o.w = f2bfu(v1.z) | (f2bfu(v1.w) << 16);
    *(int4*)((unsigned short*)(wsb + XBF_OFF) + gid) = o;
  } else if (bid < 2048 + 2304) {
    const unsigned e = (bid - 2048) * 256 + threadIdx.x;  // < 589824
    const unsigned kt = e >> 13, r2 = e & 8191;
    const unsigned kg = r2 >> 11, r3 = r2 & 2047, o = r3 >> 3, j = r3 & 7;
    const unsigned ck = kt * 32 + kg * 8 + j;
    const unsigned k = ck >> 8, c = ck & 255;
    const float v = w_dcn[((size_t)o * C1_ + c) * 9 + k];
    ((unsigned short*)(wsb + WA_OFF))[e] = (unsigned short)f2bfu(v);
  } else {
    const int wb = bid - (2048 + 2304);
    if (wb == 0) {
      const int o = threadIdx.x;
      float inv = bn_gamma[o] * rsqrtf(bn_var[o] + 1e-5f);
      ((float*)(wsb + BN_OFF))[o] = inv;
      ((float*)(wsb + BN_OFF))[256 + o] = bn_beta[o] - bn_mean[o] * inv;
    }
    const unsigned e = wb * 256 + threadIdx.x;  // < 73728
    const unsigned kt = e >> 10, kg = (e >> 8) & 3, o = (e >> 3) & 31, j = e & 7;
    const unsigned ck = kt * 32 + kg * 8 + j;
    const unsigned k = ck >> 8, c = ck & 255;
    const float v = (o < 27) ? w_om[((size_t)o * C1_ + c) * 9 + k] : 0.f;
    ((unsigned short*)(wsb + WOM_OFF))[e] = (unsigned short)f2bfu(v);
  }
}

// ---------------------------------------------------------------------------
// om_gemm: unchanged from R7.
// ---------------------------------------------------------------------------
__global__ __launch_bounds__(256) void om_gemm(const float* __restrict__ b_om,
                                               char* __restrict__ wsb) {
  __shared__ short Ald[2][2048];
  __shared__ short Bld[2][2048];
  __shared__ float omld[32][33];

  int b, h, ph;
  decode_bid512(blockIdx.x, b, h, ph);
  const int tid = threadIdx.x;
  const int lane = tid & 63, wid = tid >> 6;
  const int wo = wid >> 1, wp = wid & 1;
  const int p = tid & 31;
  const int cr = tid >> 5;

  const unsigned short* Wom = (const unsigned short*)(wsb + WOM_OFF);
  const unsigned short* xbf =
      (const unsigned short*)(wsb + XBF_OFF) + (size_t)b * C1_ * HW_;

  f32x4 acc = (f32x4){0.f, 0.f, 0.f, 0.f};

  auto stageA = [&](int s, int buf) {
    gload_lds16((const char*)(Wom + (size_t)s * 2048) + tid * 16,
                (char*)&Ald[buf][0] + tid * 16);
  };

  auto produce = [&](int s, int4& pk) {
    const int k = s >> 2;
    const int c0 = (s & 3) * 64 + cr * 8;
    const int hh = h - 1 + k / 3;
    const int ww = ph * 32 + p - 1 + k % 3;
    const bool v = ((unsigned)hh < (unsigned)H_) && ((unsigned)ww < (unsigned)W_);
    const unsigned short* pl = xbf + (size_t)c0 * HW_ + (v ? hh * W_ + ww : 0);
    unsigned u[8];
#pragma unroll
    for (int i = 0; i < 8; ++i) u[i] = v ? (unsigned)pl[(size_t)i * HW_] : 0u;
    pk.x = u[0] | (u[1] << 16);
    pk.y = u[2] | (u[3] << 16);
    pk.z = u[4] | (u[5] << 16);
    pk.w = u[6] | (u[7] << 16);
  };

  const int bslot = (cr >> 2) * 1024 + (cr & 3) * 256 + p * 8;

  auto compute = [&](int buf) {
    const int kg = lane >> 4, rr = lane & 15;
#pragma unroll
    for (int kh = 0; kh < 2; ++kh) {
      bf16x8 af = *(const bf16x8*)&Ald[buf][kh * 1024 + kg * 256 + (wo * 16 + rr) * 8];
      bf16x8 bfr = *(const bf16x8*)&Bld[buf][kh * 1024 + kg * 256 + (wp * 16 + rr) * 8];
      acc = __builtin_amdgcn_mfma_f32_16x16x32_bf16(af, bfr, acc, 0, 0, 0);
    }
  };

  {
    int4 pk;
    produce(0, pk);
    *(int4*)&Bld[0][bslot] = pk;
    stageA(0, 0);
  }
  __syncthreads();

  for (int s = 0; s < 36; ++s) {
    const int cur = s & 1, nxt = cur ^ 1;
    const bool pre = (s < 35);
    int4 pk;
    if (pre) {
      produce(s + 1, pk);
      stageA(s + 1, nxt);
    }
    compute(cur);
    if (pre) *(int4*)&Bld[nxt][bslot] = pk;
    __syncthreads();
  }

  {
    const int rr = lane & 15, rh = lane >> 4;
#pragma unroll
    for (int r = 0; r < 4; ++r) {
      const int oc = wo * 16 + rh * 4 + r;
      omld[oc][wp * 16 + rr] = acc[r];
    }
  }
  __syncthreads();

  if (tid < 32) {
    const int pc = tid;
    float a[27];
#pragma unroll
    for (int oc = 0; oc < 27; ++oc) a[oc] = omld[oc][pc] + b_om[oc];

    int2* midx = (int2*)(wsb + MIDX_OFF);
    float4* mwgt = (float4*)(wsb + MWGT_OFF);
    const int pcol = ph * 32 + pc;
#pragma unroll
    for (int k = 0; k < 9; ++k) {
      float dy = fminf(fmaxf(a[2 * k], -6.f), 6.f);
      float dx = fminf(fmaxf(a[2 * k + 1], -6.f), 6.f);
      float m = 1.f / (1.f + expf(-a[18 + k]));
      float py = (float)(h - 1 + k / 3) + dy;
      float px = (float)(pcol - 1 + k % 3) + dx;
      float y0f = floorf(py), x0f = floorf(px);
      float ly = py - y0f, lx = px - x0f;
      int y0 = (int)y0f, x0 = (int)x0f;
      int y1 = y0 + 1, x1 = x0 + 1;
      const bool vy0 = ((unsigned)y0 < (unsigned)H_);
      const bool vy1 = ((unsigned)y1 < (unsigned)H_);
      const bool vx0 = ((unsigned)x0 < (unsigned)W_);
      const bool vx1 = ((unsigned)x1 < (unsigned)W_);
      int y0c = min(max(y0, 0), H_ - 1), y1c = min(max(y1, 0), H_ - 1);
      int x0c = min(max(x0, 0), W_ - 1), x1c = min(max(x1, 0), W_ - 1);
      const int xbc = min(max(x0, 0), W_ - 2);
      float wx0 = 0.f, wx1 = 0.f;
      if (vx0) { if (x0c == xbc) wx0 += 1.f - lx; else wx1 += 1.f - lx; }
      if (vx1) { if (x1c == xbc) wx0 += lx; else wx1 += lx; }
      const float wy0 = vy0 ? (1.f - ly) : 0.f;
      const float wy1 = vy1 ? ly : 0.f;
      const size_t e = ((size_t)b * KK_ + k) * HW_ + h * W_ + pcol;
      midx[e] = make_int2(y0c * W_ + xbc, y1c * W_ + xbc);
      mwgt[e] = make_float4(m * wy0 * wx0, m * wy0 * wx1, m * wy1 * wx0,
                            m * wy1 * wx1);
    }
  }
}

// ---------------------------------------------------------------------------
// dcn_mfma: counted-vmcnt schedule. Per body t (steady state):
//   [meta prefetch (t%4==1)] [stageA(t+1): 4 gload_lds] <SB>
//   [issue gathers(t+2): 16 loads] compute(t)
//   pack(t+1) (compiler-counted vmcnt completes old gathers) -> ds_write
//   asm vmcnt(16) lgkm(0)  -> A-stage complete, NEW gathers stay in flight
//   s_barrier
// Gathers get a full step of latency cover ACROSS the barrier (T3/T4).
// ---------------------------------------------------------------------------
__global__ __launch_bounds__(512, 4) void dcn_mfma(const char* __restrict__ wsb,
                                                   float* __restrict__ out) {
  __shared__ short Ald[2][16384];
  __shared__ short Bld[2][2048];

  int b, h, ph;
  decode_bid512(blockIdx.x, b, h, ph);
  const int tid = threadIdx.x;
  const int lane = tid & 63, wid = tid >> 6;
  const int p = tid & 31;
  const int cr = tid >> 5;

  const unsigned short* Wa = (const unsigned short*)(wsb + WA_OFF);
  const unsigned short* xbf =
      (const unsigned short*)(wsb + XBF_OFF) + (size_t)b * C1_ * HW_;
  const int pg = h * W_ + ph * 32 + p;
  const int2* midx = (const int2*)(wsb + MIDX_OFF) + (size_t)b * KK_ * HW_ + pg;
  const float4* mwgt =
      (const float4*)(wsb + MWGT_OFF) + (size_t)b * KK_ * HW_ + pg;

  f32x4 acc[2][2];
#pragma unroll
  for (int i = 0; i < 2; ++i)
#pragma unroll
    for (int j = 0; j < 2; ++j) acc[i][j] = (f32x4){0.f, 0.f, 0.f, 0.f};

  auto stageA = [&](int s, int buf) {
    const char* src = (const char*)(Wa + (size_t)s * 16384);
#pragma unroll
    for (int r = 0; r < 4; ++r) {
      const int chunk = r * 512 + tid;
      gload_lds16(src + chunk * 16, (char*)&Ald[buf][0] + chunk * 16);
    }
  };

  // gathers for step s using meta mi (16 scattered ushort loads)
  auto issue = [&](int s, unsigned short (&rg)[16], const int2 mi) {
    const unsigned short* base = xbf + (size_t)((s & 3) * 64 + cr * 4) * HW_;
#pragma unroll
    for (int i = 0; i < 4; ++i) {
      rg[4 * i + 0] = base[mi.x];
      rg[4 * i + 1] = base[mi.x + 1];
      rg[4 * i + 2] = base[mi.y];
      rg[4 * i + 3] = base[mi.y + 1];
      base += HW_;
    }
  };

  auto pack = [&](const unsigned short (&rg)[16], const float4 mw, int2& pk) {
    unsigned bf[4];
#pragma unroll
    for (int i = 0; i < 4; ++i) {
      float v = mw.x * bfl(rg[4 * i]) + mw.y * bfl(rg[4 * i + 1]) +
                mw.z * bfl(rg[4 * i + 2]) + mw.w * bfl(rg[4 * i + 3]);
      bf[i] = f2bfu(v);
    }
    pk.x = bf[0] | (bf[1] << 16);
    pk.y = bf[2] | (bf[3] << 16);
  };

  const int bslot = (cr >> 3) * 1024 + ((cr >> 1) & 3) * 256 + p * 8 + (cr & 1) * 4;

  auto compute = [&](int buf) {
    const int kg = lane >> 4, rr = lane & 15;
    bf16x8 af[2][2], bfr[2][2];
#pragma unroll
    for (int kh = 0; kh < 2; ++kh) {
#pragma unroll
      for (int fm = 0; fm < 2; ++fm)
        af[fm][kh] = *(const bf16x8*)&Ald[buf][kh * 8192 + kg * 2048 +
                                              (wid * 32 + fm * 16 + rr) * 8];
#pragma unroll
      for (int fn = 0; fn < 2; ++fn)
        bfr[fn][kh] =
            *(const bf16x8*)&Bld[buf][kh * 1024 + kg * 256 + (fn * 16 + rr) * 8];
    }
#pragma unroll
    for (int kh = 0; kh < 2; ++kh)
#pragma unroll
      for (int fm = 0; fm < 2; ++fm)
#pragma unroll
        for (int fn = 0; fn < 2; ++fn)
          acc[fm][fn] = __builtin_amdgcn_mfma_f32_16x16x32_bf16(
              af[fm][kh], bfr[fn][kh], acc[fm][fn], 0, 0, 0);
  };

  unsigned short rgA[16], rgB[16];
  int2 miCur, miNext;
  float4 mwCur, mwNext;

  // ---- prologue ----
  miCur = midx[0];
  mwCur = mwgt[0];
  stageA(0, 0);
  __builtin_amdgcn_sched_barrier(0);
  issue(0, rgA, miCur);
  {
    int2 pk;
    pack(rgA, mwCur, pk);          // auto-wait drains rgA (and older)
    *(int2*)&Bld[0][bslot] = pk;
  }
  issue(1, rgB, miCur);            // in flight across the barrier
  asm volatile("s_waitcnt vmcnt(16) lgkmcnt(0)" ::: "memory");
  __builtin_amdgcn_s_barrier();
  __builtin_amdgcn_sched_barrier(0);

  // ---- main loop: pairs t = 2tp, 2tp+1 for tp = 0..16 (t = 0..33) ----
  for (int tp = 0; tp < 17; ++tp) {
    const int t = tp * 2;
    if ((tp & 1) == 0) {
      // bodyA: t%4==0  (issue miCur, pack mwCur)
      stageA(t + 1, 1);
      __builtin_amdgcn_sched_barrier(0);
      issue(t + 2, rgA, miCur);
      compute(0);
      {
        int2 pk;
        pack(rgB, mwCur, pk);
        *(int2*)&Bld[1][bslot] = pk;
      }
      asm volatile("s_waitcnt vmcnt(16) lgkmcnt(0)" ::: "memory");
      __builtin_amdgcn_s_barrier();
      __builtin_amdgcn_sched_barrier(0);
      // bodyB: t%4==1  (load Next meta; issue miCur, pack mwCur)
      {
        const int kn = (t + 4) >> 2;  // == (t+1+3)>>2
        miNext = midx[(size_t)kn * HW_];
        mwNext = mwgt[(size_t)kn * HW_];
      }
      stageA(t + 2, 0);
      __builtin_amdgcn_sched_barrier(0);
      issue(t + 3, rgB, miCur);
      compute(1);
      {
        int2 pk;
        pack(rgA, mwCur, pk);
        *(int2*)&Bld[0][bslot] = pk;
      }
      asm volatile("s_waitcnt vmcnt(16) lgkmcnt(0)" ::: "memory");
      __builtin_amdgcn_s_barrier();
      __builtin_amdgcn_sched_barrier(0);
    } else {
      // bodyA: t%4==2  (issue miNext, pack mwCur)
      stageA(t + 1, 1);
      __builtin_amdgcn_sched_barrier(0);
      issue(t + 2, rgA, miNext);
      compute(0);
      {
        int2 pk;
        pack(rgB, mwCur, pk);
        *(int2*)&Bld[1][bslot] = pk;
      }
      asm volatile("s_waitcnt vmcnt(16) lgkmcnt(0)" ::: "memory");
      __builtin_amdgcn_s_barrier();
      __builtin_amdgcn_sched_barrier(0);
      // bodyB: t%4==3  (issue miNext, pack mwNext, promote)
      stageA(t + 2, 0);
      __builtin_amdgcn_sched_barrier(0);
      issue(t + 3, rgB, miNext);
      compute(1);
      {
        int2 pk;
        pack(rgA, mwNext, pk);
        *(int2*)&Bld[0][bslot] = pk;
      }
      miCur = miNext;
      mwCur = mwNext;
      asm volatile("s_waitcnt vmcnt(16) lgkmcnt(0)" ::: "memory");
      __builtin_amdgcn_s_barrier();
      __builtin_amdgcn_sched_barrier(0);
    }
  }

  // ---- tail: t = 34 (no issue), t = 35 (compute only) ----
  stageA(35, 1);
  __builtin_amdgcn_sched_barrier(0);
  compute(0);
  {
    int2 pk;
    pack(rgB, mwCur, pk);
    *(int2*)&Bld[1][bslot] = pk;
  }
  asm volatile("s_waitcnt vmcnt(0) lgkmcnt(0)" ::: "memory");
  __builtin_amdgcn_s_barrier();
  __builtin_amdgcn_sched_barrier(0);
  compute(1);

  // epilogue: BN + SiLU + store
  const float* bninv = (const float*)(wsb + BN_OFF);
  const float* bnbb = bninv + 256;
  const int rr = lane & 15, rh = lane >> 4;
#pragma unroll
  for (int fm = 0; fm < 2; ++fm) {
#pragma unroll
    for (int r = 0; r < 4; ++r) {
      const int o = wid * 32 + fm * 16 + rh * 4 + r;
      const float inv = bninv[o], bb = bnbb[o];
#pragma unroll
      for (int fn = 0; fn < 2; ++fn) {
        float t = acc[fm][fn][r] * inv + bb;
        float s = t / (1.f + expf(-t));
        out[(size_t)(b * C2_ + o) * HW_ + h * W_ + ph * 32 + fn * 16 + rr] = s;
      }
    }
  }
}

// ---------------------------------------------------------------------------
extern "C" void kernel_launch(void* const* d_in, const int* in_sizes, int n_in,
                              void* d_out, int out_size, void* d_ws,
                              size_t ws_size, hipStream_t stream) {
  const float* x = (const float*)d_in[0];
  const float* w_om = (const float*)d_in[1];
  const float* b_om = (const float*)d_in[2];
  const float* w_dcn = (const float*)d_in[3];
  const float* bn_gamma = (const float*)d_in[4];
  const float* bn_beta = (const float*)d_in[5];
  const float* bn_mean = (const float*)d_in[6];
  const float* bn_var = (const float*)d_in[7];
  float* out = (float*)d_out;
  char* wsb = (char*)d_ws;

  prep<<<2048 + 2304 + 288, 256, 0, stream>>>(x, w_om, w_dcn, bn_gamma,
                                              bn_beta, bn_mean, bn_var, wsb);
  om_gemm<<<512, 256, 0, stream>>>(b_om, wsb);
  dcn_mfma<<<512, 512, 0, stream>>>(wsb, out);
}